// Round 1
// 508.892 us; speedup vs baseline: 1.0826x; 1.0826x over previous
//
#include <hip/hip_runtime.h>
#include <cmath>

#define BB 4
#define LL 2048
#define DD 1024
#define HH 8
#define MM (BB * LL)   // 8192 rows

struct Gammas { float lg2[8]; };
struct MMArgs { const ushort* Bt[4]; void* C[4]; int emode[4]; };

typedef __attribute__((ext_vector_type(8))) short bf16x8;
typedef __attribute__((ext_vector_type(4))) float f32x4;

__device__ __forceinline__ ushort f2bf(float f) {
    uint u = __builtin_bit_cast(uint, f);
    uint r = (u + 0x7fffu + ((u >> 16) & 1u)) >> 16;
    return (ushort)r;
}
__device__ __forceinline__ float bf2f(ushort h) {
    uint u = ((uint)h) << 16;
    return __builtin_bit_cast(float, u);
}
__device__ __forceinline__ void gload16(const void* g, void* l) {
    __builtin_amdgcn_global_load_lds((const __attribute__((address_space(1))) void*)g,
                                     (__attribute__((address_space(3))) void*)l, 16, 0, 0);
}

// ---------------------------------------------------------------------------
// xpos table: tbl[l*64 + i] = {cos*scale, sin*scale, cos/scale, sin/scale}
// ---------------------------------------------------------------------------
__global__ void xpos_table_kernel(float4* __restrict__ tbl) {
    int tid = blockIdx.x * blockDim.x + threadIdx.x;
    if (tid >= LL * 64) return;
    int l = tid >> 6, i = tid & 63;
    float inv = powf(10000.0f, -(float)i / 64.0f);
    float ang = (float)l * inv;
    float s = sinf(ang), c = cosf(ang);
    float base = (2.0f * (float)i + 51.2f) / 179.2f;
    float sc = powf(base, (float)l / 512.0f);
    tbl[tid] = make_float4(c * sc, s * sc, c / sc, s / sc);
}

__global__ __launch_bounds__(256) void cast_kernel(const float* __restrict__ X,
                                                   ushort* __restrict__ Xb) {
    int i = (blockIdx.x * 256 + threadIdx.x) * 4;
    float4 v = *(const float4*)&X[i];
    ushort4 o;
    o.x = f2bf(v.x); o.y = f2bf(v.y); o.z = f2bf(v.z); o.w = f2bf(v.w);
    *(ushort4*)&Xb[i] = o;
}

// ---------------------------------------------------------------------------
// Weight transpose+cast: W[k][n] (flat or per-head (h,d,e)) -> Wt[n][k] bf16
// ---------------------------------------------------------------------------
__global__ __launch_bounds__(256) void wtrans_kernel(const float* __restrict__ W,
                                                     ushort* __restrict__ Wt, int perhead) {
    __shared__ float T[64][68];
    const int k0 = blockIdx.y * 64, n0 = blockIdx.x * 64;
    const int t = threadIdx.x;
    for (int f = t; f < 64 * 16; f += 256) {
        int kk = f >> 4, s = f & 15;
        int n = n0 + s * 4;
        size_t src = perhead ? (size_t)(n >> 7) * 131072 + (size_t)(k0 + kk) * 128 + (n & 127)
                             : (size_t)(k0 + kk) * 1024 + n;
        *(float4*)&T[kk][s * 4] = *(const float4*)&W[src];
    }
    __syncthreads();
    for (int f = t; f < 64 * 8; f += 256) {
        int n = f >> 3, s = f & 7;
        __align__(16) ushort tmp[8];
        #pragma unroll
        for (int j = 0; j < 8; j++) tmp[j] = f2bf(T[s * 8 + j][n]);
        *(uint4*)&Wt[(size_t)(n0 + n) * 1024 + k0 + s * 8] = *(uint4*)tmp;
    }
}

// ---------------------------------------------------------------------------
// bf16 MFMA GEMM: C = A[8192x1024] * Bt^T, multi-output (4 weight/out sets).
// emode: 1 xpos up->bf16, 2 xpos down->bf16, 3 silu->bf16, 4 plain->fp32,
//        5 V-transposed store (Vt[b][v][l] bf16)
// 2-phase pipeline (T3 minimal): double-buffered LDS, next tile's
// global_load_lds issued BEFORE compute on current tile, one barrier/K-step.
// ---------------------------------------------------------------------------
__global__ __launch_bounds__(256) void mm_kernel(
    const ushort* __restrict__ A, MMArgs args, const float4* __restrict__ tbl)
{
    __shared__ __align__(16) ushort As[2][128 * 32];
    __shared__ __align__(16) ushort Bs[2][128 * 32];
    const int t = threadIdx.x;
    const int w = t >> 6, lane = t & 63;
    const int ln = lane & 15, quad = lane >> 4;
    const int which = blockIdx.x >> 3;
    const ushort* Bt = args.Bt[which];
    void* Cv = args.C[which];
    const int emode = args.emode[which];
    const int n0 = (blockIdx.x & 7) * 128, m0 = blockIdx.y * 128;
    const int wm = w & 1, wn = w >> 1;

    f32x4 acc[4][4];
    const f32x4 fzero = {0.f, 0.f, 0.f, 0.f};
    #pragma unroll
    for (int i = 0; i < 4; i++)
        #pragma unroll
        for (int j = 0; j < 4; j++) acc[i][j] = fzero;

    const int srow = w * 32 + (lane >> 2);
    const int scol = (lane & 3) * 8;
    const ushort* ga  = A  + (size_t)(m0 + srow) * 1024 + scol;
    const ushort* ga2 = ga + 16 * 1024;
    const ushort* gb  = Bt + (size_t)(n0 + srow) * 1024 + scol;
    const ushort* gb2 = gb + 16 * 1024;
    const int lo1 = (w * 32) * 32;
    const int lo2 = (w * 32 + 16) * 32;

    // prologue: stage tile 0 into buffer 0
    gload16(ga, &As[0][lo1]);
    gload16(ga2, &As[0][lo2]);
    gload16(gb, &Bs[0][lo1]);
    gload16(gb2, &Bs[0][lo2]);
    __syncthreads();

    for (int kt = 0; kt < 1024; kt += 32) {
        const int cur = (kt >> 5) & 1;
        if (kt < 1024 - 32) {
            const int nk = kt + 32;
            gload16(ga + nk, &As[cur ^ 1][lo1]);
            gload16(ga2 + nk, &As[cur ^ 1][lo2]);
            gload16(gb + nk, &Bs[cur ^ 1][lo1]);
            gload16(gb2 + nk, &Bs[cur ^ 1][lo2]);
        }
        bf16x8 am[4], bn[4];
        #pragma unroll
        for (int i = 0; i < 4; i++)
            am[i] = *(const bf16x8*)&As[cur][(wm * 64 + i * 16 + ln) * 32 + quad * 8];
        #pragma unroll
        for (int i = 0; i < 4; i++)
            bn[i] = *(const bf16x8*)&Bs[cur][(wn * 64 + i * 16 + ln) * 32 + quad * 8];
        #pragma unroll
        for (int mi = 0; mi < 4; mi++)
            #pragma unroll
            for (int ni = 0; ni < 4; ni++)
                acc[mi][ni] = __builtin_amdgcn_mfma_f32_16x16x32_bf16(
                    am[mi], bn[ni], acc[mi][ni], 0, 0, 0);
        __syncthreads();
    }

    #pragma unroll
    for (int mi = 0; mi < 4; mi++) {
        #pragma unroll
        for (int ni = 0; ni < 4; ni++) {
            const int row0 = m0 + wm * 64 + mi * 16 + quad * 4;
            const int e = wn * 64 + ni * 16 + ln;       // col within head
            const int col = n0 + e;
            if (emode == 5) {
                const int b = row0 >> 11, l0 = row0 & (LL - 1);
                ushort4 pk;
                pk.x = f2bf(acc[mi][ni][0]); pk.y = f2bf(acc[mi][ni][1]);
                pk.z = f2bf(acc[mi][ni][2]); pk.w = f2bf(acc[mi][ni][3]);
                *(ushort4*)&((ushort*)Cv)[((size_t)(b * 1024 + col)) * 2048 + l0] = pk;
                continue;
            }
            #pragma unroll
            for (int r = 0; r < 4; r++) {
                float v = acc[mi][ni][r];
                if (emode == 1 || emode == 2) {
                    float4 tt = tbl[(size_t)((row0 + r) & (LL - 1)) * 64 + (e >> 1)];
                    float cc = (emode == 1) ? tt.x : tt.z;
                    float ss = (emode == 1) ? tt.y : tt.w;
                    float partner = __shfl_xor(v, 1);
                    float rot = (e & 1) ? partner : -partner;
                    v = v * cc + rot * ss;
                } else if (emode == 3) {
                    v = v / (1.0f + expf(-v));
                }
                if (emode == 4)
                    ((float*)Cv)[(size_t)(row0 + r) * 1024 + col] = v;
                else
                    ((ushort*)Cv)[(size_t)(row0 + r) * 1024 + col] = f2bf(v);
            }
        }
    }
}

// ---------------------------------------------------------------------------
// Retention (MFMA, balanced): block z handles query blocks z and 31-z.
// Q frags in registers; K/V register-prefetched; S via transposed-operand
// MFMA -> b64 LDS writes; per-head decay cutoff.
// ---------------------------------------------------------------------------
__global__ __launch_bounds__(256) void ret_kernel(
    const ushort* __restrict__ Qb, const ushort* __restrict__ Kb,
    const ushort* __restrict__ Vt, float* __restrict__ Y, Gammas gp)
{
    __shared__ __align__(16) ushort Ks[64 * 136];
    __shared__ __align__(16) ushort Vs[128 * 72];
    __shared__ __align__(16) ushort Ss[64 * 72];

    const int t = threadIdx.x;
    const int w = t >> 6, lane = t & 63, ln = lane & 15, quad = lane >> 4;
    const int bh = blockIdx.y, b = bh >> 3, h = bh & 7;
    const float lg2 = gp.lg2[h];
    const size_t qkbase = (size_t)b * LL * 1024 + (size_t)h * 128;
    const size_t vtbase = ((size_t)b * 1024 + h * 128) * 2048;

    // decay cutoff: skip chunks where max decay < 2^-34
    const int cap = (int)((34.0f / (-lg2) + 63.0f) * 0.015625f);

    float dmk[4], drr[4];
    #pragma unroll
    for (int kt = 0; kt < 4; kt++)
        dmk[kt] = exp2f(-(float)(kt * 16 + quad * 4) * lg2);
    #pragma unroll
    for (int r = 0; r < 4; r++)
        drr[r] = exp2f(-(float)r * lg2);

    // staging indices
    const int krow = t >> 4, kc = (t & 15) * 8;      // K: 4 x (16-row step)
    const int vrow = t >> 3, vc = (t & 7) * 8;       // V: 4 x (32-row step)

    for (int seg = 0; seg < 2; seg++) {
        const int qb = seg ? 31 - blockIdx.x : blockIdx.x;
        const int n0 = qb * 64;

        bf16x8 aq[4];
        #pragma unroll
        for (int ks = 0; ks < 4; ks++)
            aq[ks] = *(const bf16x8*)&Qb[qkbase + (size_t)(n0 + 16 * w + ln) * 1024
                                         + ks * 32 + quad * 8];
        f32x4 y[8];
        const f32x4 fzero = {0.f, 0.f, 0.f, 0.f};
        #pragma unroll
        for (int vt = 0; vt < 8; vt++) y[vt] = fzero;

        int cmin = qb - cap; if (cmin < 0) cmin = 0;

        uint4 kreg[4], vreg[4];
        {
            const int m0 = cmin * 64;
            #pragma unroll
            for (int i = 0; i < 4; i++)
                kreg[i] = *(const uint4*)&Kb[qkbase + (size_t)(m0 + krow + i * 16) * 1024 + kc];
            #pragma unroll
            for (int i = 0; i < 4; i++)
                vreg[i] = *(const uint4*)&Vt[vtbase + (size_t)(vrow + i * 32) * 2048 + m0 + vc];
        }

        for (int c = cmin; c <= qb; c++) {
            const int m0 = c * 64;
            __syncthreads();
            #pragma unroll
            for (int i = 0; i < 4; i++)
                *(uint4*)&Ks[(krow + i * 16) * 136 + kc] = kreg[i];
            #pragma unroll
            for (int i = 0; i < 4; i++)
                *(uint4*)&Vs[(vrow + i * 32) * 72 + vc] = vreg[i];
            __syncthreads();
            if (c < qb) {
                const int m1 = m0 + 64;
                #pragma unroll
                for (int i = 0; i < 4; i++)
                    kreg[i] = *(const uint4*)&Kb[qkbase + (size_t)(m1 + krow + i * 16) * 1024 + kc];
                #pragma unroll
                for (int i = 0; i < 4; i++)
                    vreg[i] = *(const uint4*)&Vt[vtbase + (size_t)(vrow + i * 32) * 2048 + m1 + vc];
            }

            // S^T blocks: mfma(bk, aq) -> lane holds S[n=16w+ln][m=kt*16+quad*4+r]
            f32x4 s4[4];
            #pragma unroll
            for (int kt = 0; kt < 4; kt++) s4[kt] = fzero;
            #pragma unroll
            for (int ks = 0; ks < 4; ks++) {
                #pragma unroll
                for (int kt = 0; kt < 4; kt++) {
                    bf16x8 bk = *(const bf16x8*)&Ks[(kt * 16 + ln) * 136 + ks * 32 + quad * 8];
                    s4[kt] = __builtin_amdgcn_mfma_f32_16x16x32_bf16(bk, aq[ks], s4[kt], 0, 0, 0);
                }
            }

            const float dq = exp2f((float)(n0 - m0 + 16 * w + ln) * lg2);
            if (c == qb) {
                #pragma unroll
                for (int kt = 0; kt < 4; kt++) {
                    const float db = dq * dmk[kt];
                    ushort4 pk;
                    pk.x = f2bf((kt * 16 + quad * 4 + 0 <= 16 * w + ln) ? s4[kt][0] * db * drr[0] : 0.f);
                    pk.y = f2bf((kt * 16 + quad * 4 + 1 <= 16 * w + ln) ? s4[kt][1] * db * drr[1] : 0.f);
                    pk.z = f2bf((kt * 16 + quad * 4 + 2 <= 16 * w + ln) ? s4[kt][2] * db * drr[2] : 0.f);
                    pk.w = f2bf((kt * 16 + quad * 4 + 3 <= 16 * w + ln) ? s4[kt][3] * db * drr[3] : 0.f);
                    *(ushort4*)&Ss[(16 * w + ln) * 72 + kt * 16 + quad * 4] = pk;
                }
            } else {
                #pragma unroll
                for (int kt = 0; kt < 4; kt++) {
                    const float db = dq * dmk[kt];
                    ushort4 pk;
                    pk.x = f2bf(s4[kt][0] * db * drr[0]);
                    pk.y = f2bf(s4[kt][1] * db * drr[1]);
                    pk.z = f2bf(s4[kt][2] * db * drr[2]);
                    pk.w = f2bf(s4[kt][3] * db * drr[3]);
                    *(ushort4*)&Ss[(16 * w + ln) * 72 + kt * 16 + quad * 4] = pk;
                }
            }

            // Y += S * V   (Ss rows are wave-private: no barrier needed)
            #pragma unroll
            for (int ks2 = 0; ks2 < 2; ks2++) {
                bf16x8 as = *(const bf16x8*)&Ss[(16 * w + ln) * 72 + ks2 * 32 + quad * 8];
                #pragma unroll
                for (int vt = 0; vt < 8; vt++) {
                    bf16x8 bv = *(const bf16x8*)&Vs[(vt * 16 + ln) * 72 + ks2 * 32 + quad * 8];
                    y[vt] = __builtin_amdgcn_mfma_f32_16x16x32_bf16(as, bv, y[vt], 0, 0, 0);
                }
            }
        }

        #pragma unroll
        for (int vt = 0; vt < 8; vt++)
            #pragma unroll
            for (int r = 0; r < 4; r++)
                Y[(size_t)(b * LL + n0 + 16 * w + quad * 4 + r) * 1024
                  + h * 128 + vt * 16 + ln] = y[vt][r];
    }
}

// ---------------------------------------------------------------------------
// GroupNorm + affine + gate
// ---------------------------------------------------------------------------
__global__ __launch_bounds__(256) void gn_gate_kernel(
    const float* __restrict__ Y, const ushort* __restrict__ G,
    const float* __restrict__ gnw, const float* __restrict__ gnb,
    ushort* __restrict__ Z)
{
    const int t = threadIdx.x;
    const int g = blockIdx.x * 4 + (t >> 6);
    const int lane = t & 63;
    const size_t r = (size_t)(g >> 3);
    const int h = g & 7;
    const int e = h * 128 + lane * 2;
    const size_t base = r * 1024 + e;
    float2 y = *(const float2*)&Y[base];
    float s = y.x + y.y;
    float sq = y.x * y.x + y.y * y.y;
    #pragma unroll
    for (int off = 32; off >= 1; off >>= 1) {
        s  += __shfl_xor(s, off, 64);
        sq += __shfl_xor(sq, off, 64);
    }
    float mean = s * 0.0078125f;
    float var = sq * 0.0078125f - mean * mean;
    float rstd = rsqrtf(var + 1e-5f);
    float2 gw = *(const float2*)&gnw[e];
    float2 gb = *(const float2*)&gnb[e];
    uint gpk = *(const uint*)&G[base];
    float g0 = bf2f((ushort)(gpk & 0xffff));
    float g1 = bf2f((ushort)(gpk >> 16));
    uint o0 = f2bf(((y.x - mean) * rstd * gw.x + gb.x) * g0);
    uint o1 = f2bf(((y.y - mean) * rstd * gw.y + gb.y) * g1);
    *(uint*)&Z[base] = o0 | (o1 << 16);
}

// ---------------------------------------------------------------------------
extern "C" void kernel_launch(void* const* d_in, const int* in_sizes, int n_in,
                              void* d_out, int out_size, void* d_ws, size_t ws_size,
                              hipStream_t stream) {
    const float* X   = (const float*)d_in[0];
    const float* Wq  = (const float*)d_in[1];
    const float* Wk  = (const float*)d_in[2];
    const float* Wv  = (const float*)d_in[3];
    const float* Wg  = (const float*)d_in[4];
    const float* Wo  = (const float*)d_in[5];
    const float* gnw = (const float*)d_in[6];
    const float* gnb = (const float*)d_in[7];
    float* out = (float*)d_out;

    const size_t MB = 1u << 20;
    char* base = (char*)d_ws;
    float4* tbl = (float4*)base;                        // 2 MB
    ushort* Xb  = (ushort*)(base + 2 * MB);             // 16 MB
    ushort* Wqt = (ushort*)(base + 18 * MB);
    ushort* Wkt = (ushort*)(base + 20 * MB);
    ushort* Wvt = (ushort*)(base + 22 * MB);
    ushort* Wgt = (ushort*)(base + 24 * MB);
    ushort* Wot = (ushort*)(base + 26 * MB);
    ushort* Qb  = (ushort*)(base + 28 * MB);            // 16 MB (later Z)
    ushort* Kb  = (ushort*)(base + 44 * MB);            // 16 MB
    ushort* Gb  = (ushort*)(base + 60 * MB);            // 16 MB
    ushort* Vt  = (ushort*)(base + 76 * MB);            // 16 MB
    float*  Yp  = (float*) (base + 92 * MB);            // 32 MB -> 124 MB
    ushort* Zb  = Qb;

    Gammas gp;
    for (int h = 0; h < 8; h++) {
        double lin = log(1.0 / 32.0) +
                     (log(1.0 / 512.0) - log(1.0 / 32.0)) * (double)h / 7.0;
        float gamma = 1.0f - expf((float)lin);
        gp.lg2[h] = log2f(gamma);
    }

    xpos_table_kernel<<<(LL * 64) / 256, 256, 0, stream>>>(tbl);
    cast_kernel<<<MM * 1024 / 1024, 256, 0, stream>>>(X, Xb);

    dim3 wgrid(16, 16);
    wtrans_kernel<<<wgrid, 256, 0, stream>>>(Wq, Wqt, 1);
    wtrans_kernel<<<wgrid, 256, 0, stream>>>(Wk, Wkt, 1);
    wtrans_kernel<<<wgrid, 256, 0, stream>>>(Wv, Wvt, 1);
    wtrans_kernel<<<wgrid, 256, 0, stream>>>(Wg, Wgt, 0);
    wtrans_kernel<<<wgrid, 256, 0, stream>>>(Wo, Wot, 0);

    // fused Q/K/V/G projections (V written directly transposed into Vt)
    MMArgs qa;
    qa.Bt[0] = Wqt; qa.Bt[1] = Wkt; qa.Bt[2] = Wvt; qa.Bt[3] = Wgt;
    qa.C[0] = Qb;   qa.C[1] = Kb;   qa.C[2] = Vt;   qa.C[3] = Gb;
    qa.emode[0] = 1; qa.emode[1] = 2; qa.emode[2] = 5; qa.emode[3] = 3;
    mm_kernel<<<dim3(32, 64), 256, 0, stream>>>(Xb, qa, tbl);

    ret_kernel<<<dim3(16, 32), 256, 0, stream>>>(Qb, Kb, Vt, Yp, gp);

    gn_gate_kernel<<<(MM * HH) / 4, 256, 0, stream>>>(Yp, Gb, gnw, gnb, Zb);

    MMArgs oa;
    oa.Bt[0] = Wot; oa.Bt[1] = Wot; oa.Bt[2] = Wot; oa.Bt[3] = Wot;
    oa.C[0] = out;  oa.C[1] = out;  oa.C[2] = out;  oa.C[3] = out;
    oa.emode[0] = 4; oa.emode[1] = 4; oa.emode[2] = 4; oa.emode[3] = 4;
    mm_kernel<<<dim3(8, 64), 256, 0, stream>>>(Zb, oa, tbl);
}

// Round 2
// 490.316 us; speedup vs baseline: 1.1236x; 1.0379x over previous
//
#include <hip/hip_runtime.h>
#include <cmath>

#define BB 4
#define LL 2048
#define DD 1024
#define HH 8
#define MM (BB * LL)   // 8192 rows

struct Gammas { float lg2[8]; };
struct MMArgs { const ushort* Bt[4]; void* C[4]; int emode[4]; };

typedef __attribute__((ext_vector_type(8))) short bf16x8;
typedef __attribute__((ext_vector_type(4))) float f32x4;

__device__ __forceinline__ ushort f2bf(float f) {
    uint u = __builtin_bit_cast(uint, f);
    uint r = (u + 0x7fffu + ((u >> 16) & 1u)) >> 16;
    return (ushort)r;
}
__device__ __forceinline__ float bf2f(ushort h) {
    uint u = ((uint)h) << 16;
    return __builtin_bit_cast(float, u);
}
__device__ __forceinline__ void gload16(const void* g, void* l) {
    __builtin_amdgcn_global_load_lds((const __attribute__((address_space(1))) void*)g,
                                     (__attribute__((address_space(3))) void*)l, 16, 0, 0);
}

// ---------------------------------------------------------------------------
// xpos table: tbl[l*64 + i] = {cos*scale, sin*scale, cos/scale, sin/scale}
// ---------------------------------------------------------------------------
__global__ void xpos_table_kernel(float4* __restrict__ tbl) {
    int tid = blockIdx.x * blockDim.x + threadIdx.x;
    if (tid >= LL * 64) return;
    int l = tid >> 6, i = tid & 63;
    float inv = powf(10000.0f, -(float)i / 64.0f);
    float ang = (float)l * inv;
    float s = sinf(ang), c = cosf(ang);
    float base = (2.0f * (float)i + 51.2f) / 179.2f;
    float sc = powf(base, (float)l / 512.0f);
    tbl[tid] = make_float4(c * sc, s * sc, c / sc, s / sc);
}

__global__ __launch_bounds__(256) void cast_kernel(const float* __restrict__ X,
                                                   ushort* __restrict__ Xb) {
    int i = (blockIdx.x * 256 + threadIdx.x) * 4;
    float4 v = *(const float4*)&X[i];
    ushort4 o;
    o.x = f2bf(v.x); o.y = f2bf(v.y); o.z = f2bf(v.z); o.w = f2bf(v.w);
    *(ushort4*)&Xb[i] = o;
}

// ---------------------------------------------------------------------------
// Weight transpose+cast: W[k][n] (flat or per-head (h,d,e)) -> Wt[n][k] bf16
// ---------------------------------------------------------------------------
__global__ __launch_bounds__(256) void wtrans_kernel(const float* __restrict__ W,
                                                     ushort* __restrict__ Wt, int perhead) {
    __shared__ float T[64][68];
    const int k0 = blockIdx.y * 64, n0 = blockIdx.x * 64;
    const int t = threadIdx.x;
    for (int f = t; f < 64 * 16; f += 256) {
        int kk = f >> 4, s = f & 15;
        int n = n0 + s * 4;
        size_t src = perhead ? (size_t)(n >> 7) * 131072 + (size_t)(k0 + kk) * 128 + (n & 127)
                             : (size_t)(k0 + kk) * 1024 + n;
        *(float4*)&T[kk][s * 4] = *(const float4*)&W[src];
    }
    __syncthreads();
    for (int f = t; f < 64 * 8; f += 256) {
        int n = f >> 3, s = f & 7;
        __align__(16) ushort tmp[8];
        #pragma unroll
        for (int j = 0; j < 8; j++) tmp[j] = f2bf(T[s * 8 + j][n]);
        *(uint4*)&Wt[(size_t)(n0 + n) * 1024 + k0 + s * 8] = *(uint4*)tmp;
    }
}

// ---------------------------------------------------------------------------
// bf16 MFMA GEMM: C = A[8192x1024] * Bt^T, multi-output (4 weight/out sets).
// emode: 1 xpos up->bf16, 2 xpos down->bf16, 3 silu->bf16, 4 plain->fp32,
//        5 V-transposed store (Vt[b][v][l] bf16)
// 2-phase pipeline: double-buffered LDS, next tile's global_load_lds issued
// BEFORE compute on current tile, one barrier/K-step.
// ---------------------------------------------------------------------------
__global__ __launch_bounds__(256) void mm_kernel(
    const ushort* __restrict__ A, MMArgs args, const float4* __restrict__ tbl)
{
    __shared__ __align__(16) ushort As[2][128 * 32];
    __shared__ __align__(16) ushort Bs[2][128 * 32];
    const int t = threadIdx.x;
    const int w = t >> 6, lane = t & 63;
    const int ln = lane & 15, quad = lane >> 4;
    const int which = blockIdx.x >> 3;
    const ushort* Bt = args.Bt[which];
    void* Cv = args.C[which];
    const int emode = args.emode[which];
    const int n0 = (blockIdx.x & 7) * 128, m0 = blockIdx.y * 128;
    const int wm = w & 1, wn = w >> 1;

    f32x4 acc[4][4];
    const f32x4 fzero = {0.f, 0.f, 0.f, 0.f};
    #pragma unroll
    for (int i = 0; i < 4; i++)
        #pragma unroll
        for (int j = 0; j < 4; j++) acc[i][j] = fzero;

    const int srow = w * 32 + (lane >> 2);
    const int scol = (lane & 3) * 8;
    const ushort* ga  = A  + (size_t)(m0 + srow) * 1024 + scol;
    const ushort* ga2 = ga + 16 * 1024;
    const ushort* gb  = Bt + (size_t)(n0 + srow) * 1024 + scol;
    const ushort* gb2 = gb + 16 * 1024;
    const int lo1 = (w * 32) * 32;
    const int lo2 = (w * 32 + 16) * 32;

    // prologue: stage tile 0 into buffer 0
    gload16(ga, &As[0][lo1]);
    gload16(ga2, &As[0][lo2]);
    gload16(gb, &Bs[0][lo1]);
    gload16(gb2, &Bs[0][lo2]);
    __syncthreads();

    for (int kt = 0; kt < 1024; kt += 32) {
        const int cur = (kt >> 5) & 1;
        if (kt < 1024 - 32) {
            const int nk = kt + 32;
            gload16(ga + nk, &As[cur ^ 1][lo1]);
            gload16(ga2 + nk, &As[cur ^ 1][lo2]);
            gload16(gb + nk, &Bs[cur ^ 1][lo1]);
            gload16(gb2 + nk, &Bs[cur ^ 1][lo2]);
        }
        bf16x8 am[4], bn[4];
        #pragma unroll
        for (int i = 0; i < 4; i++)
            am[i] = *(const bf16x8*)&As[cur][(wm * 64 + i * 16 + ln) * 32 + quad * 8];
        #pragma unroll
        for (int i = 0; i < 4; i++)
            bn[i] = *(const bf16x8*)&Bs[cur][(wn * 64 + i * 16 + ln) * 32 + quad * 8];
        #pragma unroll
        for (int mi = 0; mi < 4; mi++)
            #pragma unroll
            for (int ni = 0; ni < 4; ni++)
                acc[mi][ni] = __builtin_amdgcn_mfma_f32_16x16x32_bf16(
                    am[mi], bn[ni], acc[mi][ni], 0, 0, 0);
        __syncthreads();
    }

    #pragma unroll
    for (int mi = 0; mi < 4; mi++) {
        #pragma unroll
        for (int ni = 0; ni < 4; ni++) {
            const int row0 = m0 + wm * 64 + mi * 16 + quad * 4;
            const int e = wn * 64 + ni * 16 + ln;       // col within head
            const int col = n0 + e;
            if (emode == 5) {
                const int b = row0 >> 11, l0 = row0 & (LL - 1);
                ushort4 pk;
                pk.x = f2bf(acc[mi][ni][0]); pk.y = f2bf(acc[mi][ni][1]);
                pk.z = f2bf(acc[mi][ni][2]); pk.w = f2bf(acc[mi][ni][3]);
                *(ushort4*)&((ushort*)Cv)[((size_t)(b * 1024 + col)) * 2048 + l0] = pk;
                continue;
            }
            #pragma unroll
            for (int r = 0; r < 4; r++) {
                float v = acc[mi][ni][r];
                if (emode == 1 || emode == 2) {
                    float4 tt = tbl[(size_t)((row0 + r) & (LL - 1)) * 64 + (e >> 1)];
                    float cc = (emode == 1) ? tt.x : tt.z;
                    float ss = (emode == 1) ? tt.y : tt.w;
                    float partner = __shfl_xor(v, 1);
                    float rot = (e & 1) ? partner : -partner;
                    v = v * cc + rot * ss;
                } else if (emode == 3) {
                    v = v / (1.0f + expf(-v));
                }
                if (emode == 4)
                    ((float*)Cv)[(size_t)(row0 + r) * 1024 + col] = v;
                else
                    ((ushort*)Cv)[(size_t)(row0 + r) * 1024 + col] = f2bf(v);
            }
        }
    }
}

// ---------------------------------------------------------------------------
// Retention (MFMA, balanced) + FUSED GroupNorm/gate epilogue.
// Block z handles query blocks z and 31-z of its (b,h). Each block holds the
// full 128-dim v-range for its 64 rows -> mean/var via in-quad shfl reduce,
// affine + silu-gate applied in registers, Z written bf16 directly.
// XCD swizzle: all 16 x-blocks of one (b,h) land on one XCD (K/V set = 4MB).
// ---------------------------------------------------------------------------
__global__ __launch_bounds__(256) void ret_kernel(
    const ushort* __restrict__ Qb, const ushort* __restrict__ Kb,
    const ushort* __restrict__ Vt, const ushort* __restrict__ Gb,
    const float* __restrict__ gnw, const float* __restrict__ gnb,
    ushort* __restrict__ Z, Gammas gp)
{
    __shared__ __align__(16) ushort Ks[64 * 136];
    __shared__ __align__(16) ushort Vs[128 * 72];
    __shared__ __align__(16) ushort Ss[64 * 72];

    const int t = threadIdx.x;
    const int w = t >> 6, lane = t & 63, ln = lane & 15, quad = lane >> 4;

    // XCD-aware swizzle (512 blocks, 512%8==0 -> bijective):
    // xcd = gid%8 gets bh in [4*xcd, 4*xcd+3], all 16 x-blocks of each.
    const int gid = blockIdx.y * 16 + blockIdx.x;
    const int xcd = gid & 7, within = gid >> 3;
    const int bh = (xcd << 2) | (within >> 4);
    const int xb = within & 15;

    const int b = bh >> 3, h = bh & 7;
    const float lg2 = gp.lg2[h];
    const size_t qkbase = (size_t)b * LL * 1024 + (size_t)h * 128;
    const size_t vtbase = ((size_t)b * 1024 + h * 128) * 2048;

    // decay cutoff: skip chunks where max decay < 2^-34
    const int cap = (int)((34.0f / (-lg2) + 63.0f) * 0.015625f);

    float dmk[4], drr[4];
    #pragma unroll
    for (int kt = 0; kt < 4; kt++)
        dmk[kt] = exp2f(-(float)(kt * 16 + quad * 4) * lg2);
    #pragma unroll
    for (int r = 0; r < 4; r++)
        drr[r] = exp2f(-(float)r * lg2);

    // groupnorm affine params (cols identical for both segs)
    float gwv[8], gbv[8];
    #pragma unroll
    for (int vt = 0; vt < 8; vt++) {
        gwv[vt] = gnw[h * 128 + vt * 16 + ln];
        gbv[vt] = gnb[h * 128 + vt * 16 + ln];
    }

    // staging indices
    const int krow = t >> 4, kc = (t & 15) * 8;      // K: 4 x (16-row step)
    const int vrow = t >> 3, vc = (t & 7) * 8;       // V: 4 x (32-row step)

    for (int seg = 0; seg < 2; seg++) {
        const int qb = seg ? 31 - xb : xb;
        const int n0 = qb * 64;

        bf16x8 aq[4];
        #pragma unroll
        for (int ks = 0; ks < 4; ks++)
            aq[ks] = *(const bf16x8*)&Qb[qkbase + (size_t)(n0 + 16 * w + ln) * 1024
                                         + ks * 32 + quad * 8];
        f32x4 y[8];
        const f32x4 fzero = {0.f, 0.f, 0.f, 0.f};
        #pragma unroll
        for (int vt = 0; vt < 8; vt++) y[vt] = fzero;

        int cmin = qb - cap; if (cmin < 0) cmin = 0;

        uint4 kreg[4], vreg[4];
        {
            const int m0 = cmin * 64;
            #pragma unroll
            for (int i = 0; i < 4; i++)
                kreg[i] = *(const uint4*)&Kb[qkbase + (size_t)(m0 + krow + i * 16) * 1024 + kc];
            #pragma unroll
            for (int i = 0; i < 4; i++)
                vreg[i] = *(const uint4*)&Vt[vtbase + (size_t)(vrow + i * 32) * 2048 + m0 + vc];
        }

        for (int c = cmin; c <= qb; c++) {
            const int m0 = c * 64;
            __syncthreads();
            #pragma unroll
            for (int i = 0; i < 4; i++)
                *(uint4*)&Ks[(krow + i * 16) * 136 + kc] = kreg[i];
            #pragma unroll
            for (int i = 0; i < 4; i++)
                *(uint4*)&Vs[(vrow + i * 32) * 72 + vc] = vreg[i];
            __syncthreads();
            if (c < qb) {
                const int m1 = m0 + 64;
                #pragma unroll
                for (int i = 0; i < 4; i++)
                    kreg[i] = *(const uint4*)&Kb[qkbase + (size_t)(m1 + krow + i * 16) * 1024 + kc];
                #pragma unroll
                for (int i = 0; i < 4; i++)
                    vreg[i] = *(const uint4*)&Vt[vtbase + (size_t)(vrow + i * 32) * 2048 + m1 + vc];
            }

            // S^T blocks: mfma(bk, aq) -> lane holds S[n=16w+ln][m=kt*16+quad*4+r]
            f32x4 s4[4];
            #pragma unroll
            for (int kt = 0; kt < 4; kt++) s4[kt] = fzero;
            #pragma unroll
            for (int ks = 0; ks < 4; ks++) {
                #pragma unroll
                for (int kt = 0; kt < 4; kt++) {
                    bf16x8 bk = *(const bf16x8*)&Ks[(kt * 16 + ln) * 136 + ks * 32 + quad * 8];
                    s4[kt] = __builtin_amdgcn_mfma_f32_16x16x32_bf16(bk, aq[ks], s4[kt], 0, 0, 0);
                }
            }

            const float dq = exp2f((float)(n0 - m0 + 16 * w + ln) * lg2);
            if (c == qb) {
                #pragma unroll
                for (int kt = 0; kt < 4; kt++) {
                    const float db = dq * dmk[kt];
                    ushort4 pk;
                    pk.x = f2bf((kt * 16 + quad * 4 + 0 <= 16 * w + ln) ? s4[kt][0] * db * drr[0] : 0.f);
                    pk.y = f2bf((kt * 16 + quad * 4 + 1 <= 16 * w + ln) ? s4[kt][1] * db * drr[1] : 0.f);
                    pk.z = f2bf((kt * 16 + quad * 4 + 2 <= 16 * w + ln) ? s4[kt][2] * db * drr[2] : 0.f);
                    pk.w = f2bf((kt * 16 + quad * 4 + 3 <= 16 * w + ln) ? s4[kt][3] * db * drr[3] : 0.f);
                    *(ushort4*)&Ss[(16 * w + ln) * 72 + kt * 16 + quad * 4] = pk;
                }
            } else {
                #pragma unroll
                for (int kt = 0; kt < 4; kt++) {
                    const float db = dq * dmk[kt];
                    ushort4 pk;
                    pk.x = f2bf(s4[kt][0] * db * drr[0]);
                    pk.y = f2bf(s4[kt][1] * db * drr[1]);
                    pk.z = f2bf(s4[kt][2] * db * drr[2]);
                    pk.w = f2bf(s4[kt][3] * db * drr[3]);
                    *(ushort4*)&Ss[(16 * w + ln) * 72 + kt * 16 + quad * 4] = pk;
                }
            }

            // Y += S * V   (Ss rows are wave-private: no barrier needed)
            #pragma unroll
            for (int ks2 = 0; ks2 < 2; ks2++) {
                bf16x8 as = *(const bf16x8*)&Ss[(16 * w + ln) * 72 + ks2 * 32 + quad * 8];
                #pragma unroll
                for (int vt = 0; vt < 8; vt++) {
                    bf16x8 bv = *(const bf16x8*)&Vs[(vt * 16 + ln) * 72 + ks2 * 32 + quad * 8];
                    y[vt] = __builtin_amdgcn_mfma_f32_16x16x32_bf16(as, bv, y[vt], 0, 0, 0);
                }
            }
        }

        // fused GroupNorm + affine + gate epilogue (row = n0+16w+quad*4+r,
        // its 128 v-values live in the 16 ln-lanes of this quad x 8 vt regs)
        #pragma unroll
        for (int r = 0; r < 4; r++) {
            float s = 0.f, sq = 0.f;
            #pragma unroll
            for (int vt = 0; vt < 8; vt++) {
                float v = y[vt][r];
                s += v; sq += v * v;
            }
            #pragma unroll
            for (int off = 8; off >= 1; off >>= 1) {
                s  += __shfl_xor(s, off, 64);
                sq += __shfl_xor(sq, off, 64);
            }
            float mean = s * 0.0078125f;
            float var = sq * 0.0078125f - mean * mean;
            float rstd = rsqrtf(var + 1e-5f);
            const size_t row = (size_t)(b * LL + n0 + 16 * w + quad * 4 + r);
            #pragma unroll
            for (int vt = 0; vt < 8; vt++) {
                float gv = bf2f(Gb[row * 1024 + h * 128 + vt * 16 + ln]);
                float o = (y[vt][r] - mean) * rstd * gwv[vt] + gbv[vt];
                Z[row * 1024 + h * 128 + vt * 16 + ln] = f2bf(o * gv);
            }
        }
    }
}

// ---------------------------------------------------------------------------
extern "C" void kernel_launch(void* const* d_in, const int* in_sizes, int n_in,
                              void* d_out, int out_size, void* d_ws, size_t ws_size,
                              hipStream_t stream) {
    const float* X   = (const float*)d_in[0];
    const float* Wq  = (const float*)d_in[1];
    const float* Wk  = (const float*)d_in[2];
    const float* Wv  = (const float*)d_in[3];
    const float* Wg  = (const float*)d_in[4];
    const float* Wo  = (const float*)d_in[5];
    const float* gnw = (const float*)d_in[6];
    const float* gnb = (const float*)d_in[7];
    float* out = (float*)d_out;

    const size_t MB = 1u << 20;
    char* base = (char*)d_ws;
    float4* tbl = (float4*)base;                        // 2 MB
    ushort* Xb  = (ushort*)(base + 2 * MB);             // 16 MB
    ushort* Wqt = (ushort*)(base + 18 * MB);
    ushort* Wkt = (ushort*)(base + 20 * MB);
    ushort* Wvt = (ushort*)(base + 22 * MB);
    ushort* Wgt = (ushort*)(base + 24 * MB);
    ushort* Wot = (ushort*)(base + 26 * MB);
    ushort* Qb  = (ushort*)(base + 28 * MB);            // 16 MB
    ushort* Kb  = (ushort*)(base + 44 * MB);            // 16 MB
    ushort* Gb  = (ushort*)(base + 60 * MB);            // 16 MB
    ushort* Vt  = (ushort*)(base + 76 * MB);            // 16 MB
    ushort* Zb  = (ushort*)(base + 92 * MB);            // 16 MB (own buffer:
                                                        // ret reads Qb concurrently)

    Gammas gp;
    for (int h = 0; h < 8; h++) {
        double lin = log(1.0 / 32.0) +
                     (log(1.0 / 512.0) - log(1.0 / 32.0)) * (double)h / 7.0;
        float gamma = 1.0f - expf((float)lin);
        gp.lg2[h] = log2f(gamma);
    }

    xpos_table_kernel<<<(LL * 64) / 256, 256, 0, stream>>>(tbl);
    cast_kernel<<<MM * 1024 / 1024, 256, 0, stream>>>(X, Xb);

    dim3 wgrid(16, 16);
    wtrans_kernel<<<wgrid, 256, 0, stream>>>(Wq, Wqt, 1);
    wtrans_kernel<<<wgrid, 256, 0, stream>>>(Wk, Wkt, 1);
    wtrans_kernel<<<wgrid, 256, 0, stream>>>(Wv, Wvt, 1);
    wtrans_kernel<<<wgrid, 256, 0, stream>>>(Wg, Wgt, 0);
    wtrans_kernel<<<wgrid, 256, 0, stream>>>(Wo, Wot, 0);

    // fused Q/K/V/G projections (V written directly transposed into Vt)
    MMArgs qa;
    qa.Bt[0] = Wqt; qa.Bt[1] = Wkt; qa.Bt[2] = Wvt; qa.Bt[3] = Wgt;
    qa.C[0] = Qb;   qa.C[1] = Kb;   qa.C[2] = Vt;   qa.C[3] = Gb;
    qa.emode[0] = 1; qa.emode[1] = 2; qa.emode[2] = 5; qa.emode[3] = 3;
    mm_kernel<<<dim3(32, 64), 256, 0, stream>>>(Xb, qa, tbl);

    // retention + fused groupnorm/gate -> Zb (bf16)
    ret_kernel<<<dim3(16, 32), 256, 0, stream>>>(Qb, Kb, Vt, Gb, gnw, gnb, Zb, gp);

    MMArgs oa;
    oa.Bt[0] = Wot; oa.Bt[1] = Wot; oa.Bt[2] = Wot; oa.Bt[3] = Wot;
    oa.C[0] = out;  oa.C[1] = out;  oa.C[2] = out;  oa.C[3] = out;
    oa.emode[0] = 4; oa.emode[1] = 4; oa.emode[2] = 4; oa.emode[3] = 4;
    mm_kernel<<<dim3(8, 64), 256, 0, stream>>>(Zb, oa, tbl);
}